// Round 1
// baseline (170.463 us; speedup 1.0000x reference)
//
#include <hip/hip_runtime.h>

// Retention forward: O = ((Q K^T) * scale * lambda_h^(i-j) * causal) V
// B=2, H=16, S=2048, D=64, fp32 in/out. bf16 MFMA compute (tolerance is bf16-grade).

#define S_LEN 2048
#define DHEAD 64
#define TQ 64
#define TK 64
#define NQT (S_LEN / TQ)   // 32
#define LDK 72             // padded LDS row length (bf16 elems): 144B rows, 16B-aligned

typedef float  f32x4  __attribute__((ext_vector_type(4)));
typedef short  bf16x8 __attribute__((ext_vector_type(8)));
typedef unsigned short u16x8 __attribute__((ext_vector_type(8)));

static __device__ __forceinline__ unsigned short f2bf(float f) {
    // round-to-nearest-even f32 -> bf16 (inputs are finite; NaN path irrelevant)
    unsigned int u = __float_as_uint(f);
    u += 0x7FFFu + ((u >> 16) & 1u);
    return (unsigned short)(u >> 16);
}

__global__ void retention_fwd(const float* __restrict__ qg,
                              const float* __restrict__ kg,
                              const float* __restrict__ vg,
                              float* __restrict__ og) {
    const int qt    = (NQT - 1) - (int)blockIdx.x;  // heaviest q-tiles dispatch first
    const int bh    = (int)blockIdx.y;              // b*H + h
    const int h     = bh & 15;
    const int qbase = qt * TQ;

    const int tid  = (int)threadIdx.x;
    const int wv   = tid >> 6;   // wave 0..3, owns q rows [wv*16, wv*16+16)
    const int ln   = tid & 63;
    const int quad = ln >> 4;    // 0..3
    const int lnlo = ln & 15;

    const float sh    = log2f(1.0f - exp2f(-5.0f - (float)h));  // decay log2-rate, < 0
    const float scale = 0.125f;                                  // D^-0.5

    __shared__ __align__(16) unsigned short Ks[TK * LDK];        // K tile [pos][d], bf16
    __shared__ __align__(16) unsigned short Vt[DHEAD * LDK];     // V tile transposed [d][pos]
    __shared__ __align__(16) unsigned short Ws[4 * 16 * LDK];    // per-wave P tile [qrow][pos]

    const size_t base = (size_t)bh * S_LEN * DHEAD;
    const float* qp = qg + base;
    const float* kp = kg + base;
    const float* vp = vg + base;

    // ---- Q A-fragments, loaded once, kept in registers ----
    // A[m = lnlo][k = kstep*32 + quad*8 + j]
    bf16x8 aQ[2];
    {
        const float* qrow = qp + (size_t)(qbase + wv * 16 + lnlo) * DHEAD;
#pragma unroll
        for (int ks = 0; ks < 2; ++ks) {
            const float* p = qrow + ks * 32 + quad * 8;
            bf16x8 a;
#pragma unroll
            for (int j = 0; j < 8; ++j) a[j] = (short)f2bf(p[j]);
            aQ[ks] = a;
        }
    }

    // row decay factors: rf[r] = 2^((i - qbase) * sh), i-row = wv*16 + quad*4 + r
    float rf[4];
#pragma unroll
    for (int r = 0; r < 4; ++r)
        rf[r] = exp2f((float)(wv * 16 + quad * 4 + r) * sh);

    // skip k-tiles whose max weight < 2^-30 (neglected mass bounded ~1e-6)
    const int dmax  = (int)(30.0f / (-sh));
    const int lo    = qbase - 63 - dmax;
    const int ktmin = (lo <= 0) ? 0 : ((lo + 63) >> 6);

    f32x4 o[4];
#pragma unroll
    for (int nt = 0; nt < 4; ++nt) o[nt] = (f32x4){0.f, 0.f, 0.f, 0.f};

    for (int kt = ktmin; kt <= qt; ++kt) {
        const int kbase = kt * TK;
        __syncthreads();  // previous tile's LDS reads done before overwrite

        // ---- stage K tile: [pos][d] fp32 -> bf16 LDS, coalesced float4 loads ----
        {
            const int r  = tid >> 2;          // 0..63
            const int c0 = (tid & 3) * 16;    // 0,16,32,48
            const float* p = kp + (size_t)(kbase + r) * DHEAD + c0;
            const f32x4 x0 = *(const f32x4*)(p + 0);
            const f32x4 x1 = *(const f32x4*)(p + 4);
            const f32x4 x2 = *(const f32x4*)(p + 8);
            const f32x4 x3 = *(const f32x4*)(p + 12);
            u16x8 w0, w1;
            w0[0]=f2bf(x0[0]); w0[1]=f2bf(x0[1]); w0[2]=f2bf(x0[2]); w0[3]=f2bf(x0[3]);
            w0[4]=f2bf(x1[0]); w0[5]=f2bf(x1[1]); w0[6]=f2bf(x1[2]); w0[7]=f2bf(x1[3]);
            w1[0]=f2bf(x2[0]); w1[1]=f2bf(x2[1]); w1[2]=f2bf(x2[2]); w1[3]=f2bf(x2[3]);
            w1[4]=f2bf(x3[0]); w1[5]=f2bf(x3[1]); w1[6]=f2bf(x3[2]); w1[7]=f2bf(x3[3]);
            *(u16x8*)&Ks[r * LDK + c0]     = w0;
            *(u16x8*)&Ks[r * LDK + c0 + 8] = w1;
        }

        // ---- stage V tile transposed: Vt[d][pos]; scalar loads coalesced across lanes,
        //      8 consecutive pos per lane -> one 16B LDS write, bank-balanced ----
#pragma unroll
        for (int i = 0; i < 2; ++i) {
            const int pos0 = wv * 8 + i * 32;
            const float* p = vp + (size_t)(kbase + pos0) * DHEAD + ln;
            u16x8 t;
#pragma unroll
            for (int j = 0; j < 8; ++j) t[j] = f2bf(p[(size_t)j * DHEAD]);
            *(u16x8*)&Vt[ln * LDK + pos0] = t;
        }
        __syncthreads();

        // ---- S = Q K^T : 8 MFMAs -> 16x64 scores per wave ----
        f32x4 acc[4];
#pragma unroll
        for (int nt = 0; nt < 4; ++nt) acc[nt] = (f32x4){0.f, 0.f, 0.f, 0.f};
#pragma unroll
        for (int nt = 0; nt < 4; ++nt) {
#pragma unroll
            for (int ks = 0; ks < 2; ++ks) {
                // B[k=d][n=pos]: lane reads K[pos = nt*16+lnlo][d = ks*32+quad*8 + 0..7]
                const bf16x8 bk = *(const bf16x8*)&Ks[(nt * 16 + lnlo) * LDK + ks * 32 + quad * 8];
                acc[nt] = __builtin_amdgcn_mfma_f32_16x16x32_bf16(aQ[ks], bk, acc[nt], 0, 0, 0);
            }
        }

        // ---- decay * scale * causal, C-layout (row=quad*4+r, col=nt*16+lnlo),
        //      round-trip through per-wave LDS to A-layout ----
        const bool diag = (kt == qt);
#pragma unroll
        for (int nt = 0; nt < 4; ++nt) {
            const int jn = nt * 16 + lnlo;
            const float cf = scale * exp2f((float)(qbase - kbase - jn) * sh);
#pragma unroll
            for (int r = 0; r < 4; ++r) {
                const int ri = wv * 16 + quad * 4 + r;
                float wgt = acc[nt][r] * rf[r] * cf;
                if (diag && (ri < jn)) wgt = 0.0f;   // causal mask inside diagonal tile
                Ws[ri * LDK + jn] = f2bf(wgt);
            }
        }
        // same-wave LDS RAW: DS ops are in-order per wave; compiler inserts lgkmcnt

        bf16x8 aW[2];
#pragma unroll
        for (int ks = 0; ks < 2; ++ks)
            aW[ks] = *(const bf16x8*)&Ws[(wv * 16 + lnlo) * LDK + ks * 32 + quad * 8];

        // ---- O += P V : 8 MFMAs ----
#pragma unroll
        for (int nt = 0; nt < 4; ++nt) {
#pragma unroll
            for (int ks = 0; ks < 2; ++ks) {
                // B[k=pos][n=d]: lane reads Vt[d = nt*16+lnlo][pos = ks*32+quad*8 + 0..7]
                const bf16x8 bv = *(const bf16x8*)&Vt[(nt * 16 + lnlo) * LDK + ks * 32 + quad * 8];
                o[nt] = __builtin_amdgcn_mfma_f32_16x16x32_bf16(aW[ks], bv, o[nt], 0, 0, 0);
            }
        }
    }

    // ---- epilogue: C-layout scatter, 16 lanes -> 64B contiguous per store ----
    float* op = og + base;
#pragma unroll
    for (int nt = 0; nt < 4; ++nt) {
#pragma unroll
        for (int r = 0; r < 4; ++r) {
            const int row = qbase + wv * 16 + quad * 4 + r;
            op[(size_t)row * DHEAD + nt * 16 + lnlo] = o[nt][r];
        }
    }
}

extern "C" void kernel_launch(void* const* d_in, const int* in_sizes, int n_in,
                              void* d_out, int out_size, void* d_ws, size_t ws_size,
                              hipStream_t stream) {
    (void)in_sizes; (void)n_in; (void)d_ws; (void)ws_size; (void)out_size;
    const float* q = (const float*)d_in[0];
    const float* k = (const float*)d_in[1];
    const float* v = (const float*)d_in[2];
    float* o = (float*)d_out;
    dim3 grid(NQT, 32, 1);   // x: q-tile (reversed), y: b*H+h
    dim3 block(256, 1, 1);
    retention_fwd<<<grid, block, 0, stream>>>(q, k, v, o);
}

// Round 2
// 154.878 us; speedup vs baseline: 1.1006x; 1.1006x over previous
//
#include <hip/hip_runtime.h>

// Retention forward: O = ((Q K^T) * scale * lambda_h^(i-j) * causal) V
// B=2, H=16, S=2048, D=64, fp32 in/out. bf16 MFMA compute.
// Round 2: paired q-tiles (uniform 33-iter blocks) + reg->LDS double-buffered
// pipeline with a single barrier per k-iteration.

#define S_LEN 2048
#define DHEAD 64
#define TK 64
#define NQT 32
#define LDK 72   // padded LDS row (bf16 elems): rows 16B-aligned, stride 144B

typedef float  f32x4  __attribute__((ext_vector_type(4)));
typedef short  bf16x8 __attribute__((ext_vector_type(8)));
typedef unsigned short u16x8 __attribute__((ext_vector_type(8)));

static __device__ __forceinline__ unsigned short f2bf(float f) {
    unsigned int u = __float_as_uint(f);
    u += 0x7FFFu + ((u >> 16) & 1u);
    return (unsigned short)(u >> 16);
}

__global__ __launch_bounds__(256, 3)
void retention_fwd(const float* __restrict__ qg, const float* __restrict__ kg,
                   const float* __restrict__ vg, float* __restrict__ og) {
    const int pid = (int)blockIdx.x;        // 0..15
    const int bh  = (int)blockIdx.y;        // b*H + h
    const int h   = bh & 15;
    const int qtA = pid;                    // light tile: pid+1 k-iters
    const int qtB = NQT - 1 - pid;          // heavy tile: 32-pid k-iters (sum = 33)
    const int qbA = qtA * 64, qbB = qtB * 64;

    const int tid  = (int)threadIdx.x;
    const int wv   = tid >> 6;
    const int ln   = tid & 63;
    const int quad = ln >> 4;
    const int lnlo = ln & 15;

    const float sh    = log2f(1.0f - exp2f(-5.0f - (float)h));  // < 0
    const float scale = 0.125f;

    __shared__ __align__(16) unsigned short Ks[2][TK * LDK];     // K [pos][d]
    __shared__ __align__(16) unsigned short Vt[2][DHEAD * LDK];  // V^T [d][pos]
    __shared__ __align__(16) unsigned short Ws[4 * 16 * LDK];    // per-wave P [qrow][pos]

    const size_t base = (size_t)bh * S_LEN * DHEAD;
    const float* qp = qg + base;
    const float* kp = kg + base;
    const float* vp = vg + base;
    float*       op = og + base;

    // ---- Q A-fragments for both tiles, loaded once ----
    bf16x8 aQA[2], aQB[2];
    {
        const float* qa = qp + (size_t)(qbA + wv * 16 + lnlo) * DHEAD;
        const float* qb = qp + (size_t)(qbB + wv * 16 + lnlo) * DHEAD;
#pragma unroll
        for (int ks = 0; ks < 2; ++ks) {
            const float* pa = qa + ks * 32 + quad * 8;
            const float* pb = qb + ks * 32 + quad * 8;
            bf16x8 a, b;
#pragma unroll
            for (int j = 0; j < 8; ++j) { a[j] = (short)f2bf(pa[j]); b[j] = (short)f2bf(pb[j]); }
            aQA[ks] = a; aQB[ks] = b;
        }
    }

    float rf[4];
#pragma unroll
    for (int r = 0; r < 4; ++r) rf[r] = exp2f((float)(wv * 16 + quad * 4 + r) * sh);

    // decay-based k-tile skip (weights < 2^-30 dropped; error << tolerance)
    const int dmax = (int)(30.0f / (-sh));
    const int loA = qbA - 63 - dmax;  const int ktminA = (loA <= 0) ? 0 : ((loA + 63) >> 6);
    const int loB = qbB - 63 - dmax;  const int ktminB = (loB <= 0) ? 0 : ((loB + 63) >> 6);
    const int nA   = qtA - ktminA + 1;
    const int nB   = qtB - ktminB + 1;
    const int ntot = nA + nB;

    // ---- prefetch registers ----
    f32x4 pk[4];
    float pv[16];
    const int kr  = tid >> 2;          // 0..63
    const int kc0 = (tid & 3) * 16;    // 0,16,32,48

    auto prefetch = [&](int it) {
        const int kt    = (it < nA) ? (ktminA + it) : (ktminB + (it - nA));
        const int kbase = kt * TK;
        const float* p = kp + (size_t)(kbase + kr) * DHEAD + kc0;
        pk[0] = *(const f32x4*)(p + 0);
        pk[1] = *(const f32x4*)(p + 4);
        pk[2] = *(const f32x4*)(p + 8);
        pk[3] = *(const f32x4*)(p + 12);
        const float* pvp = vp + (size_t)(kbase + wv * 8) * DHEAD + ln;  // coalesced across lanes
#pragma unroll
        for (int i = 0; i < 2; ++i)
#pragma unroll
            for (int j = 0; j < 8; ++j)
                pv[i * 8 + j] = pvp[(size_t)(i * 32 + j) * DHEAD];
    };

    f32x4 o[4];
#pragma unroll
    for (int nt = 0; nt < 4; ++nt) o[nt] = (f32x4){0.f, 0.f, 0.f, 0.f};

    prefetch(0);

    for (int it = 0; it < ntot; ++it) {
        const int  buf   = it & 1;
        const bool isA   = (it < nA);
        const int  kt    = isA ? (ktminA + it) : (ktminB + (it - nA));
        const int  kbase = kt * TK;
        const int  qbase = isA ? qbA : qbB;
        const bool diag  = (kt == (isA ? qtA : qtB));

        // ---- stage prefetched regs -> LDS[buf] (bf16) ----
        {
            u16x8 w0, w1;
            w0[0]=f2bf(pk[0][0]); w0[1]=f2bf(pk[0][1]); w0[2]=f2bf(pk[0][2]); w0[3]=f2bf(pk[0][3]);
            w0[4]=f2bf(pk[1][0]); w0[5]=f2bf(pk[1][1]); w0[6]=f2bf(pk[1][2]); w0[7]=f2bf(pk[1][3]);
            w1[0]=f2bf(pk[2][0]); w1[1]=f2bf(pk[2][1]); w1[2]=f2bf(pk[2][2]); w1[3]=f2bf(pk[2][3]);
            w1[4]=f2bf(pk[3][0]); w1[5]=f2bf(pk[3][1]); w1[6]=f2bf(pk[3][2]); w1[7]=f2bf(pk[3][3]);
            *(u16x8*)&Ks[buf][kr * LDK + kc0]     = w0;
            *(u16x8*)&Ks[buf][kr * LDK + kc0 + 8] = w1;
#pragma unroll
            for (int i = 0; i < 2; ++i) {
                u16x8 t;
#pragma unroll
                for (int j = 0; j < 8; ++j) t[j] = f2bf(pv[i * 8 + j]);
                *(u16x8*)&Vt[buf][ln * LDK + wv * 8 + i * 32] = t;
            }
        }
        __syncthreads();   // single barrier per iteration (double-buffered tiles)

        if (it + 1 < ntot) prefetch(it + 1);   // overlaps compute below

        const bf16x8 aQ0 = isA ? aQA[0] : aQB[0];
        const bf16x8 aQ1 = isA ? aQA[1] : aQB[1];

        // ---- S = Q K^T ----
        f32x4 acc[4];
#pragma unroll
        for (int nt = 0; nt < 4; ++nt) acc[nt] = (f32x4){0.f, 0.f, 0.f, 0.f};
#pragma unroll
        for (int nt = 0; nt < 4; ++nt) {
            const bf16x8 bk0 = *(const bf16x8*)&Ks[buf][(nt * 16 + lnlo) * LDK + quad * 8];
            const bf16x8 bk1 = *(const bf16x8*)&Ks[buf][(nt * 16 + lnlo) * LDK + 32 + quad * 8];
            acc[nt] = __builtin_amdgcn_mfma_f32_16x16x32_bf16(aQ0, bk0, acc[nt], 0, 0, 0);
            acc[nt] = __builtin_amdgcn_mfma_f32_16x16x32_bf16(aQ1, bk1, acc[nt], 0, 0, 0);
        }

        // ---- decay * scale * causal; C-layout -> A-layout via per-wave LDS ----
#pragma unroll
        for (int nt = 0; nt < 4; ++nt) {
            const int jn = nt * 16 + lnlo;
            const float cf = scale * exp2f((float)(qbase - kbase - jn) * sh);
#pragma unroll
            for (int r = 0; r < 4; ++r) {
                const int ri = wv * 16 + quad * 4 + r;
                float wgt = acc[nt][r] * rf[r] * cf;
                if (diag && (ri < jn)) wgt = 0.0f;
                Ws[ri * LDK + jn] = f2bf(wgt);
            }
        }
        const bf16x8 aW0 = *(const bf16x8*)&Ws[(wv * 16 + lnlo) * LDK + quad * 8];
        const bf16x8 aW1 = *(const bf16x8*)&Ws[(wv * 16 + lnlo) * LDK + 32 + quad * 8];

        // ---- O += P V ----
#pragma unroll
        for (int nt = 0; nt < 4; ++nt) {
            const bf16x8 bv0 = *(const bf16x8*)&Vt[buf][(nt * 16 + lnlo) * LDK + quad * 8];
            const bf16x8 bv1 = *(const bf16x8*)&Vt[buf][(nt * 16 + lnlo) * LDK + 32 + quad * 8];
            o[nt] = __builtin_amdgcn_mfma_f32_16x16x32_bf16(aW0, bv0, o[nt], 0, 0, 0);
            o[nt] = __builtin_amdgcn_mfma_f32_16x16x32_bf16(aW1, bv1, o[nt], 0, 0, 0);
        }

        // finished tile A? dump its output, reset accumulator
        if (it == nA - 1) {
#pragma unroll
            for (int nt = 0; nt < 4; ++nt) {
#pragma unroll
                for (int r = 0; r < 4; ++r) {
                    const int row = qbA + wv * 16 + quad * 4 + r;
                    op[(size_t)row * DHEAD + nt * 16 + lnlo] = o[nt][r];
                }
                o[nt] = (f32x4){0.f, 0.f, 0.f, 0.f};
            }
        }
    }

    // tile B epilogue
#pragma unroll
    for (int nt = 0; nt < 4; ++nt)
#pragma unroll
        for (int r = 0; r < 4; ++r) {
            const int row = qbB + wv * 16 + quad * 4 + r;
            op[(size_t)row * DHEAD + nt * 16 + lnlo] = o[nt][r];
        }
}

extern "C" void kernel_launch(void* const* d_in, const int* in_sizes, int n_in,
                              void* d_out, int out_size, void* d_ws, size_t ws_size,
                              hipStream_t stream) {
    (void)in_sizes; (void)n_in; (void)d_ws; (void)ws_size; (void)out_size;
    const float* q = (const float*)d_in[0];
    const float* k = (const float*)d_in[1];
    const float* v = (const float*)d_in[2];
    float* o = (float*)d_out;
    dim3 grid(16, 32, 1);    // x: q-tile pair, y: b*H+h  (512 uniform blocks)
    dim3 block(256, 1, 1);
    retention_fwd<<<grid, block, 0, stream>>>(q, k, v, o);
}

// Round 3
// 111.616 us; speedup vs baseline: 1.5272x; 1.3876x over previous
//
#include <hip/hip_runtime.h>

// Retention forward, chunkwise-linear algorithm.
// O[i] = sum_{j<=i} lambda^(i-j) * scale * (q_i.k_j) v_j
//      = intra-chunk(64) + scale*lambda^(i_local) * q_i . S_c
// S_c = lam^C S_{c-1} + U_{c-1},  U_c[d][e] = sum_j lam^(C-j) K[j][d] V[j][e]
// B=2,H=16,S=2048,D=64 fp32. bf16 MFMA; S carried as double-bf16 (hi+lo).

#define S_LEN 2048
#define DHEAD 64
#define CHUNK 64
#define NC    32          // chunks per sequence
#define BH    32          // B*H
#define LDK   72          // padded LDS row (bf16 elems)

typedef float  f32x4  __attribute__((ext_vector_type(4)));
typedef short  bf16x8 __attribute__((ext_vector_type(8)));
typedef unsigned short u16x8 __attribute__((ext_vector_type(8)));

static __device__ __forceinline__ unsigned short f2bf(float f) {
    unsigned int u = __float_as_uint(f);
    u += 0x7FFFu + ((u >> 16) & 1u);
    return (unsigned short)(u >> 16);
}
static __device__ __forceinline__ float bf2f(unsigned short h) {
    return __uint_as_float((unsigned int)h << 16);
}

// ---------------- Phase 1: per-chunk KV summaries U_c ----------------
// U^T stored [bh][c][e][d] fp32 (contiguous d) so the scan reads coalesced.
__global__ __launch_bounds__(256)
void ret_p1(const float* __restrict__ kg, const float* __restrict__ vg,
            float* __restrict__ Ug) {
    const int c  = (int)blockIdx.x, bh = (int)blockIdx.y, h = bh & 15;
    const int tid = (int)threadIdx.x;
    const int wv = tid >> 6, ln = tid & 63, quad = ln >> 4, lnlo = ln & 15;
    const float sh = log2f(1.0f - exp2f(-5.0f - (float)h));   // < 0

    __shared__ __align__(16) unsigned short Kt[CHUNK * LDK];  // [d][j], weight folded
    __shared__ __align__(16) unsigned short Vt[CHUNK * LDK];  // [e][j]

    const size_t cb = (size_t)bh * S_LEN * DHEAD + (size_t)c * CHUNK * DHEAD;
    const float* kp = kg + cb;
    const float* vp = vg + cb;

    // transpose-stage: lane ln owns head-dim column ln, 8 consecutive positions
#pragma unroll
    for (int i = 0; i < 2; ++i) {
        const int pos0 = wv * 8 + i * 32;
        const float* pK = kp + (size_t)pos0 * DHEAD + ln;
        const float* pV = vp + (size_t)pos0 * DHEAD + ln;
        u16x8 tk, tv;
#pragma unroll
        for (int j = 0; j < 8; ++j) {
            const float w = exp2f(sh * (float)(CHUNK - pos0 - j));  // lam^(C - j_local)
            tk[j] = f2bf(pK[(size_t)j * DHEAD] * w);
            tv[j] = f2bf(pV[(size_t)j * DHEAD]);
        }
        *(u16x8*)&Kt[ln * LDK + pos0] = tk;
        *(u16x8*)&Vt[ln * LDK + pos0] = tv;
    }
    __syncthreads();

    // U[d][e]: A[m=d][k=j] = Kt rows, B[k=j][n=e] = Vt rows; wave owns d in [wv*16, +16)
    bf16x8 aK[2];
#pragma unroll
    for (int ks = 0; ks < 2; ++ks)
        aK[ks] = *(const bf16x8*)&Kt[(wv * 16 + lnlo) * LDK + ks * 32 + quad * 8];

    float* up = Ug + ((size_t)(bh * NC + c) << 12);
#pragma unroll
    for (int nt = 0; nt < 4; ++nt) {
        f32x4 acc = (f32x4){0.f, 0.f, 0.f, 0.f};
#pragma unroll
        for (int ks = 0; ks < 2; ++ks) {
            const bf16x8 bv = *(const bf16x8*)&Vt[(nt * 16 + lnlo) * LDK + ks * 32 + quad * 8];
            acc = __builtin_amdgcn_mfma_f32_16x16x32_bf16(aK[ks], bv, acc, 0, 0, 0);
        }
        // C elem (m=d=wv*16+quad*4+r, n=e=nt*16+lnlo) -> U^T[e][d]: float4 over r
        *(f32x4*)&up[(nt * 16 + lnlo) * 64 + wv * 16 + quad * 4] = acc;
    }
}

// ---------------- Phase 2: elementwise scan over chunks ----------------
// S_c = lam^C S_{c-1} + U_{c-1}; write S_c as bf16 hi/lo. Fully parallel in (e,d).
__global__ __launch_bounds__(256)
void ret_p2(const float* __restrict__ Ug,
            unsigned short* __restrict__ Shg, unsigned short* __restrict__ Slg) {
    const int eb = (int)blockIdx.x, bh = (int)blockIdx.y, h = bh & 15;
    const float sh   = log2f(1.0f - exp2f(-5.0f - (float)h));
    const float lamC = exp2f(sh * (float)CHUNK);
    const int elem = eb * 256 + (int)threadIdx.x;

    const float* up        = Ug  + ((size_t)(bh * NC) << 12) + elem;
    unsigned short* shp    = Shg + ((size_t)(bh * NC) << 12) + elem;
    unsigned short* slp    = Slg + ((size_t)(bh * NC) << 12) + elem;

    float S = 0.0f;
    float u = up[0];
    for (int c = 0; c < NC; ++c) {
        const float un = (c + 1 < NC) ? up[(size_t)(c + 1) << 12] : 0.0f;  // prefetch
        const unsigned short hi = f2bf(S);
        shp[(size_t)c << 12] = hi;
        slp[(size_t)c << 12] = f2bf(S - bf2f(hi));
        S = lamC * S + u;
        u = un;
    }
}

// ---------------- Phase 3: per-chunk output = cross + intra ----------------
__global__ __launch_bounds__(256)
void ret_p3(const float* __restrict__ qg, const float* __restrict__ kg,
            const float* __restrict__ vg,
            const unsigned short* __restrict__ Shg,
            const unsigned short* __restrict__ Slg,
            float* __restrict__ og) {
    const int c  = (int)blockIdx.x, bh = (int)blockIdx.y, h = bh & 15;
    const int tid = (int)threadIdx.x;
    const int wv = tid >> 6, ln = tid & 63, quad = ln >> 4, lnlo = ln & 15;
    const float sh    = log2f(1.0f - exp2f(-5.0f - (float)h));
    const float scale = 0.125f;

    __shared__ __align__(16) unsigned short Ks[CHUNK * LDK];   // K [pos][d]
    __shared__ __align__(16) unsigned short Vt[CHUNK * LDK];   // V^T [e][pos]
    __shared__ __align__(16) unsigned short ShL[CHUNK * LDK];  // S_hi^T [e][d]; reused as Ws
    __shared__ __align__(16) unsigned short SlL[CHUNK * LDK];  // S_lo^T [e][d]

    const size_t cb = (size_t)bh * S_LEN * DHEAD + (size_t)c * CHUNK * DHEAD;
    const float* qp = qg + cb;
    const float* kp = kg + cb;
    const float* vp = vg + cb;
    float*       op = og + cb;

    // ---- stage K [pos][d] (coalesced float4 loads, bf16 pack) ----
    {
        const int kr = tid >> 2, kc0 = (tid & 3) * 16;
        const float* p = kp + (size_t)kr * DHEAD + kc0;
        const f32x4 x0 = *(const f32x4*)(p + 0);
        const f32x4 x1 = *(const f32x4*)(p + 4);
        const f32x4 x2 = *(const f32x4*)(p + 8);
        const f32x4 x3 = *(const f32x4*)(p + 12);
        u16x8 w0, w1;
        w0[0]=f2bf(x0[0]); w0[1]=f2bf(x0[1]); w0[2]=f2bf(x0[2]); w0[3]=f2bf(x0[3]);
        w0[4]=f2bf(x1[0]); w0[5]=f2bf(x1[1]); w0[6]=f2bf(x1[2]); w0[7]=f2bf(x1[3]);
        w1[0]=f2bf(x2[0]); w1[1]=f2bf(x2[1]); w1[2]=f2bf(x2[2]); w1[3]=f2bf(x2[3]);
        w1[4]=f2bf(x3[0]); w1[5]=f2bf(x3[1]); w1[6]=f2bf(x3[2]); w1[7]=f2bf(x3[3]);
        *(u16x8*)&Ks[kr * LDK + kc0]     = w0;
        *(u16x8*)&Ks[kr * LDK + kc0 + 8] = w1;
    }
    // ---- stage V^T [e][pos] ----
#pragma unroll
    for (int i = 0; i < 2; ++i) {
        const int pos0 = wv * 8 + i * 32;
        const float* p = vp + (size_t)pos0 * DHEAD + ln;
        u16x8 t;
#pragma unroll
        for (int j = 0; j < 8; ++j) t[j] = f2bf(p[(size_t)j * DHEAD]);
        *(u16x8*)&Vt[ln * LDK + pos0] = t;
    }
    // ---- stage S_hi / S_lo tiles (straight bf16 copy) ----
    {
        const size_t sb = ((size_t)(bh * NC + c) << 12) + (size_t)tid * 16;
        const int r = tid >> 2, cc = (tid & 3) * 16;
        *(u16x8*)&ShL[r * LDK + cc]     = *(const u16x8*)(Shg + sb);
        *(u16x8*)&ShL[r * LDK + cc + 8] = *(const u16x8*)(Shg + sb + 8);
        *(u16x8*)&SlL[r * LDK + cc]     = *(const u16x8*)(Slg + sb);
        *(u16x8*)&SlL[r * LDK + cc + 8] = *(const u16x8*)(Slg + sb + 8);
    }

    // ---- Q A-fragments (raw bf16; m = local row wv*16+lnlo) ----
    bf16x8 aQ[2];
    {
        const float* qrow = qp + (size_t)(wv * 16 + lnlo) * DHEAD;
#pragma unroll
        for (int ks = 0; ks < 2; ++ks) {
            const float* p = qrow + ks * 32 + quad * 8;
            bf16x8 a;
#pragma unroll
            for (int j = 0; j < 8; ++j) a[j] = (short)f2bf(p[j]);
            aQ[ks] = a;
        }
    }
    float rf[4];
#pragma unroll
    for (int r = 0; r < 4; ++r) rf[r] = exp2f((float)(wv * 16 + quad * 4 + r) * sh);

    __syncthreads();

    // ---- cross: o = Q.S_hi + Q.S_lo (B[k=d][n=e] from S^T rows) ----
    f32x4 o[4];
#pragma unroll
    for (int nt = 0; nt < 4; ++nt) {
        f32x4 a = (f32x4){0.f, 0.f, 0.f, 0.f};
#pragma unroll
        for (int ks = 0; ks < 2; ++ks) {
            const bf16x8 bh_ = *(const bf16x8*)&ShL[(nt * 16 + lnlo) * LDK + ks * 32 + quad * 8];
            a = __builtin_amdgcn_mfma_f32_16x16x32_bf16(aQ[ks], bh_, a, 0, 0, 0);
        }
#pragma unroll
        for (int ks = 0; ks < 2; ++ks) {
            const bf16x8 bl_ = *(const bf16x8*)&SlL[(nt * 16 + lnlo) * LDK + ks * 32 + quad * 8];
            a = __builtin_amdgcn_mfma_f32_16x16x32_bf16(aQ[ks], bl_, a, 0, 0, 0);
        }
        o[nt] = a;
    }

    // ---- intra scores S = Q K^T ----
    f32x4 acc[4];
#pragma unroll
    for (int nt = 0; nt < 4; ++nt) {
        f32x4 a = (f32x4){0.f, 0.f, 0.f, 0.f};
#pragma unroll
        for (int ks = 0; ks < 2; ++ks) {
            const bf16x8 bk = *(const bf16x8*)&Ks[(nt * 16 + lnlo) * LDK + ks * 32 + quad * 8];
            a = __builtin_amdgcn_mfma_f32_16x16x32_bf16(aQ[ks], bk, a, 0, 0, 0);
        }
        acc[nt] = a;
    }

    // scale cross by scale * lam^(i_local)
#pragma unroll
    for (int nt = 0; nt < 4; ++nt)
#pragma unroll
        for (int r = 0; r < 4; ++r) o[nt][r] *= rf[r] * scale;

    __syncthreads();   // all waves done reading ShL before it becomes Ws

    // ---- decay*scale*causal on intra scores; C-layout -> A-layout via LDS ----
#pragma unroll
    for (int nt = 0; nt < 4; ++nt) {
        const int jn = nt * 16 + lnlo;
        const float cf = scale * exp2f(-(float)jn * sh);
#pragma unroll
        for (int r = 0; r < 4; ++r) {
            const int ri = wv * 16 + quad * 4 + r;
            float wgt = acc[nt][r] * rf[r] * cf;
            if (ri < jn) wgt = 0.0f;
            ShL[ri * LDK + jn] = f2bf(wgt);   // per-wave slice of ShL
        }
    }
    const bf16x8 aW0 = *(const bf16x8*)&ShL[(wv * 16 + lnlo) * LDK + quad * 8];
    const bf16x8 aW1 = *(const bf16x8*)&ShL[(wv * 16 + lnlo) * LDK + 32 + quad * 8];

    // ---- O += P V ----
#pragma unroll
    for (int nt = 0; nt < 4; ++nt) {
        const bf16x8 bv0 = *(const bf16x8*)&Vt[(nt * 16 + lnlo) * LDK + quad * 8];
        const bf16x8 bv1 = *(const bf16x8*)&Vt[(nt * 16 + lnlo) * LDK + 32 + quad * 8];
        o[nt] = __builtin_amdgcn_mfma_f32_16x16x32_bf16(aW0, bv0, o[nt], 0, 0, 0);
        o[nt] = __builtin_amdgcn_mfma_f32_16x16x32_bf16(aW1, bv1, o[nt], 0, 0, 0);
    }

    // ---- epilogue ----
#pragma unroll
    for (int nt = 0; nt < 4; ++nt)
#pragma unroll
        for (int r = 0; r < 4; ++r)
            op[(size_t)(wv * 16 + quad * 4 + r) * DHEAD + nt * 16 + lnlo] = o[nt][r];
}

// ---------------- Fallback: round-2 monolithic quadratic kernel ----------------
__global__ __launch_bounds__(256, 3)
void retention_mono(const float* __restrict__ qg, const float* __restrict__ kg,
                    const float* __restrict__ vg, float* __restrict__ og) {
    const int pid = (int)blockIdx.x;
    const int bh  = (int)blockIdx.y;
    const int h   = bh & 15;
    const int qtA = pid, qtB = 31 - pid;
    const int qbA = qtA * 64, qbB = qtB * 64;
    const int tid = (int)threadIdx.x;
    const int wv = tid >> 6, ln = tid & 63, quad = ln >> 4, lnlo = ln & 15;
    const float sh = log2f(1.0f - exp2f(-5.0f - (float)h));
    const float scale = 0.125f;
    __shared__ __align__(16) unsigned short Ks[2][64 * LDK];
    __shared__ __align__(16) unsigned short Vt[2][64 * LDK];
    __shared__ __align__(16) unsigned short Ws[64 * LDK];
    const size_t base = (size_t)bh * S_LEN * DHEAD;
    const float* qp = qg + base; const float* kp = kg + base;
    const float* vp = vg + base; float* op = og + base;
    bf16x8 aQA[2], aQB[2];
    {
        const float* qa = qp + (size_t)(qbA + wv * 16 + lnlo) * DHEAD;
        const float* qb = qp + (size_t)(qbB + wv * 16 + lnlo) * DHEAD;
#pragma unroll
        for (int ks = 0; ks < 2; ++ks) {
            const float* pa = qa + ks * 32 + quad * 8;
            const float* pb = qb + ks * 32 + quad * 8;
            bf16x8 a, b;
#pragma unroll
            for (int j = 0; j < 8; ++j) { a[j] = (short)f2bf(pa[j]); b[j] = (short)f2bf(pb[j]); }
            aQA[ks] = a; aQB[ks] = b;
        }
    }
    float rf[4];
#pragma unroll
    for (int r = 0; r < 4; ++r) rf[r] = exp2f((float)(wv * 16 + quad * 4 + r) * sh);
    const int dmax = (int)(30.0f / (-sh));
    const int loA = qbA - 63 - dmax;  const int ktminA = (loA <= 0) ? 0 : ((loA + 63) >> 6);
    const int loB = qbB - 63 - dmax;  const int ktminB = (loB <= 0) ? 0 : ((loB + 63) >> 6);
    const int nA = qtA - ktminA + 1, nB = qtB - ktminB + 1, ntot = nA + nB;
    f32x4 pk[4]; float pv[16];
    const int kr = tid >> 2, kc0 = (tid & 3) * 16;
    auto prefetch = [&](int it) {
        const int kt = (it < nA) ? (ktminA + it) : (ktminB + (it - nA));
        const float* p = kp + (size_t)(kt * 64 + kr) * DHEAD + kc0;
        pk[0] = *(const f32x4*)(p + 0);  pk[1] = *(const f32x4*)(p + 4);
        pk[2] = *(const f32x4*)(p + 8);  pk[3] = *(const f32x4*)(p + 12);
        const float* pvp = vp + (size_t)(kt * 64 + wv * 8) * DHEAD + ln;
#pragma unroll
        for (int i = 0; i < 2; ++i)
#pragma unroll
            for (int j = 0; j < 8; ++j) pv[i * 8 + j] = pvp[(size_t)(i * 32 + j) * DHEAD];
    };
    f32x4 o[4];
#pragma unroll
    for (int nt = 0; nt < 4; ++nt) o[nt] = (f32x4){0.f, 0.f, 0.f, 0.f};
    prefetch(0);
    for (int it = 0; it < ntot; ++it) {
        const int buf = it & 1;
        const bool isA = (it < nA);
        const int kt = isA ? (ktminA + it) : (ktminB + (it - nA));
        const int kbase = kt * 64;
        const int qbase = isA ? qbA : qbB;
        const bool diag = (kt == (isA ? qtA : qtB));
        {
            u16x8 w0, w1;
            w0[0]=f2bf(pk[0][0]); w0[1]=f2bf(pk[0][1]); w0[2]=f2bf(pk[0][2]); w0[3]=f2bf(pk[0][3]);
            w0[4]=f2bf(pk[1][0]); w0[5]=f2bf(pk[1][1]); w0[6]=f2bf(pk[1][2]); w0[7]=f2bf(pk[1][3]);
            w1[0]=f2bf(pk[2][0]); w1[1]=f2bf(pk[2][1]); w1[2]=f2bf(pk[2][2]); w1[3]=f2bf(pk[2][3]);
            w1[4]=f2bf(pk[3][0]); w1[5]=f2bf(pk[3][1]); w1[6]=f2bf(pk[3][2]); w1[7]=f2bf(pk[3][3]);
            *(u16x8*)&Ks[buf][kr * LDK + kc0]     = w0;
            *(u16x8*)&Ks[buf][kr * LDK + kc0 + 8] = w1;
#pragma unroll
            for (int i = 0; i < 2; ++i) {
                u16x8 t;
#pragma unroll
                for (int j = 0; j < 8; ++j) t[j] = f2bf(pv[i * 8 + j]);
                *(u16x8*)&Vt[buf][ln * LDK + wv * 8 + i * 32] = t;
            }
        }
        __syncthreads();
        if (it + 1 < ntot) prefetch(it + 1);
        const bf16x8 aQ0 = isA ? aQA[0] : aQB[0];
        const bf16x8 aQ1 = isA ? aQA[1] : aQB[1];
        f32x4 acc[4];
#pragma unroll
        for (int nt = 0; nt < 4; ++nt) acc[nt] = (f32x4){0.f, 0.f, 0.f, 0.f};
#pragma unroll
        for (int nt = 0; nt < 4; ++nt) {
            const bf16x8 bk0 = *(const bf16x8*)&Ks[buf][(nt * 16 + lnlo) * LDK + quad * 8];
            const bf16x8 bk1 = *(const bf16x8*)&Ks[buf][(nt * 16 + lnlo) * LDK + 32 + quad * 8];
            acc[nt] = __builtin_amdgcn_mfma_f32_16x16x32_bf16(aQ0, bk0, acc[nt], 0, 0, 0);
            acc[nt] = __builtin_amdgcn_mfma_f32_16x16x32_bf16(aQ1, bk1, acc[nt], 0, 0, 0);
        }
#pragma unroll
        for (int nt = 0; nt < 4; ++nt) {
            const int jn = nt * 16 + lnlo;
            const float cf = scale * exp2f((float)(qbase - kbase - jn) * sh);
#pragma unroll
            for (int r = 0; r < 4; ++r) {
                const int ri = wv * 16 + quad * 4 + r;
                float wgt = acc[nt][r] * rf[r] * cf;
                if (diag && (ri < jn)) wgt = 0.0f;
                Ws[ri * LDK + jn] = f2bf(wgt);
            }
        }
        const bf16x8 aW0 = *(const bf16x8*)&Ws[(wv * 16 + lnlo) * LDK + quad * 8];
        const bf16x8 aW1 = *(const bf16x8*)&Ws[(wv * 16 + lnlo) * LDK + 32 + quad * 8];
#pragma unroll
        for (int nt = 0; nt < 4; ++nt) {
            const bf16x8 bv0 = *(const bf16x8*)&Vt[buf][(nt * 16 + lnlo) * LDK + quad * 8];
            const bf16x8 bv1 = *(const bf16x8*)&Vt[buf][(nt * 16 + lnlo) * LDK + 32 + quad * 8];
            o[nt] = __builtin_amdgcn_mfma_f32_16x16x32_bf16(aW0, bv0, o[nt], 0, 0, 0);
            o[nt] = __builtin_amdgcn_mfma_f32_16x16x32_bf16(aW1, bv1, o[nt], 0, 0, 0);
        }
        if (it == nA - 1) {
#pragma unroll
            for (int nt = 0; nt < 4; ++nt) {
#pragma unroll
                for (int r = 0; r < 4; ++r)
                    op[(size_t)(qbA + wv * 16 + quad * 4 + r) * DHEAD + nt * 16 + lnlo] = o[nt][r];
                o[nt] = (f32x4){0.f, 0.f, 0.f, 0.f};
            }
        }
    }
#pragma unroll
    for (int nt = 0; nt < 4; ++nt)
#pragma unroll
        for (int r = 0; r < 4; ++r)
            op[(size_t)(qbB + wv * 16 + quad * 4 + r) * DHEAD + nt * 16 + lnlo] = o[nt][r];
}

extern "C" void kernel_launch(void* const* d_in, const int* in_sizes, int n_in,
                              void* d_out, int out_size, void* d_ws, size_t ws_size,
                              hipStream_t stream) {
    (void)in_sizes; (void)n_in; (void)out_size;
    const float* q = (const float*)d_in[0];
    const float* k = (const float*)d_in[1];
    const float* v = (const float*)d_in[2];
    float* o = (float*)d_out;

    const size_t U_BYTES = (size_t)BH * NC * 4096 * 4;   // 16 MB
    const size_t S_BYTES = (size_t)BH * NC * 4096 * 2;   //  8 MB each
    if (ws_size >= U_BYTES + 2 * S_BYTES) {
        float*          Ug  = (float*)d_ws;
        unsigned short* Shg = (unsigned short*)((char*)d_ws + U_BYTES);
        unsigned short* Slg = (unsigned short*)((char*)d_ws + U_BYTES + S_BYTES);
        dim3 blk(256, 1, 1);
        ret_p1<<<dim3(NC, BH, 1), blk, 0, stream>>>(k, v, Ug);
        ret_p2<<<dim3(16, BH, 1), blk, 0, stream>>>(Ug, Shg, Slg);
        ret_p3<<<dim3(NC, BH, 1), blk, 0, stream>>>(q, k, v, Shg, Slg, o);
    } else {
        retention_mono<<<dim3(16, BH, 1), dim3(256, 1, 1), 0, stream>>>(q, k, v, o);
    }
}